// Round 1
// baseline (20142.564 us; speedup 1.0000x reference)
//
#include <hip/hip_runtime.h>
#include <math.h>

#define TT  64
#define BSZ 512
#define ISZ 512
#define HSZ 1024

#define BB 64   // batch tile
#define HH 64   // hidden tile
#define KT 32   // k tile
#define PAD 4   // LDS pad (keeps 16B alignment of rows)

// One LSTM time step, fused GEMM (x@W_ih^T + h@W_hh^T for 4 gates) + pointwise.
// Each block computes a [BB x HH] tile of (b, h) outputs, all 4 gates.
__global__ __launch_bounds__(256) void lstm_step_kernel(
    const float* __restrict__ x,      // [BSZ, ISZ] slice for step t
    const float* __restrict__ hprev,  // [BSZ, HSZ] (unused when t==0)
    const float* __restrict__ Wih,    // [4*HSZ, ISZ]
    const float* __restrict__ Whh,    // [4*HSZ, HSZ]
    const float* __restrict__ bih,    // [4*HSZ]
    const float* __restrict__ bhh,    // [4*HSZ]
    float* __restrict__ cstate,       // [BSZ, HSZ] in d_ws
    float* __restrict__ hout,         // d_out + t*BSZ*HSZ
    float* __restrict__ hn,           // d_out + TT*BSZ*HSZ      (written iff t==TT-1)
    float* __restrict__ cn,           // d_out + (TT+1)*BSZ*HSZ  (written iff t==TT-1)
    int t)
{
    __shared__ float As[KT][BB + PAD];          // A tile, k-major
    __shared__ float Ws[4 * KT][HH + PAD];      // W tile, 4 gates, k-major

    const int tid = threadIdx.x;
    const int tx  = tid & 15;   // h group: cols tx*4 .. tx*4+3
    const int ty  = tid >> 4;   // b group: rows ty*4 .. ty*4+3
    const int hh0 = blockIdx.x * HH;
    const int bb0 = blockIdx.y * BB;

    float acc[4][4][4];
    #pragma unroll
    for (int g = 0; g < 4; ++g)
        #pragma unroll
        for (int i = 0; i < 4; ++i)
            #pragma unroll
            for (int j = 0; j < 4; ++j)
                acc[g][i][j] = 0.f;

    const int nk1 = ISZ / KT;                    // 16 k-tiles from x / W_ih
    const int nk2 = HSZ / KT;                    // 32 k-tiles from h / W_hh
    const int nkt = (t > 0) ? (nk1 + nk2) : nk1; // h0 == 0 -> skip h part

    // staging thread mapping: 4 threads per row, 8 consecutive k each
    const int ar = tid >> 2;          // row within tile [0,64)
    const int ac = (tid & 3) * 8;     // k offset {0,8,16,24}

    for (int kt = 0; kt < nkt; ++kt) {
        const float* Asrc; int lda; int k0;
        const float* Wsrc; int ldw;
        if (kt < nk1) { Asrc = x;     lda = ISZ; k0 = kt * KT;         Wsrc = Wih; ldw = ISZ; }
        else          { Asrc = hprev; lda = HSZ; k0 = (kt - nk1) * KT; Wsrc = Whh; ldw = HSZ; }

        __syncthreads();  // previous compute done before overwriting tiles

        // stage A: [BB=64 rows] x [KT=32 k] -> transposed into As[k][b]
        {
            const float* src = Asrc + (size_t)(bb0 + ar) * lda + (k0 + ac);
            float4 v0 = *(const float4*)(src);
            float4 v1 = *(const float4*)(src + 4);
            As[ac + 0][ar] = v0.x; As[ac + 1][ar] = v0.y;
            As[ac + 2][ar] = v0.z; As[ac + 3][ar] = v0.w;
            As[ac + 4][ar] = v1.x; As[ac + 5][ar] = v1.y;
            As[ac + 6][ar] = v1.z; As[ac + 7][ar] = v1.w;
        }
        // stage W: 4 gates x [HH=64 rows] x [KT=32 k] -> Ws[g*KT + k][n]
        #pragma unroll
        for (int g = 0; g < 4; ++g) {
            const float* src = Wsrc + (size_t)(g * HSZ + hh0 + ar) * ldw + (k0 + ac);
            float4 v0 = *(const float4*)(src);
            float4 v1 = *(const float4*)(src + 4);
            Ws[g * KT + ac + 0][ar] = v0.x; Ws[g * KT + ac + 1][ar] = v0.y;
            Ws[g * KT + ac + 2][ar] = v0.z; Ws[g * KT + ac + 3][ar] = v0.w;
            Ws[g * KT + ac + 4][ar] = v1.x; Ws[g * KT + ac + 5][ar] = v1.y;
            Ws[g * KT + ac + 6][ar] = v1.z; Ws[g * KT + ac + 7][ar] = v1.w;
        }
        __syncthreads();

        #pragma unroll 8
        for (int kk = 0; kk < KT; ++kk) {
            float4 a  = *(const float4*)&As[kk][ty * 4];
            float4 w0 = *(const float4*)&Ws[0 * KT + kk][tx * 4];
            float4 w1 = *(const float4*)&Ws[1 * KT + kk][tx * 4];
            float4 w2 = *(const float4*)&Ws[2 * KT + kk][tx * 4];
            float4 w3 = *(const float4*)&Ws[3 * KT + kk][tx * 4];
            const float av[4] = {a.x, a.y, a.z, a.w};
            const float wv[4][4] = {{w0.x, w0.y, w0.z, w0.w},
                                    {w1.x, w1.y, w1.z, w1.w},
                                    {w2.x, w2.y, w2.z, w2.w},
                                    {w3.x, w3.y, w3.z, w3.w}};
            #pragma unroll
            for (int g = 0; g < 4; ++g)
                #pragma unroll
                for (int i = 0; i < 4; ++i)
                    #pragma unroll
                    for (int j = 0; j < 4; ++j)
                        acc[g][i][j] += av[i] * wv[g][j];
        }
    }

    // epilogue: bias + activations + LSTM cell update
    #pragma unroll
    for (int j = 0; j < 4; ++j) {
        const int n = hh0 + tx * 4 + j;
        const float bi0 = bih[0 * HSZ + n] + bhh[0 * HSZ + n];
        const float bi1 = bih[1 * HSZ + n] + bhh[1 * HSZ + n];
        const float bi2 = bih[2 * HSZ + n] + bhh[2 * HSZ + n];
        const float bi3 = bih[3 * HSZ + n] + bhh[3 * HSZ + n];
        #pragma unroll
        for (int i = 0; i < 4; ++i) {
            const int b = bb0 + ty * 4 + i;
            const size_t idx = (size_t)b * HSZ + n;
            float gi = acc[0][i][j] + bi0;
            float gf = acc[1][i][j] + bi1;
            float gg = acc[2][i][j] + bi2;
            float go = acc[3][i][j] + bi3;
            float ig = 1.f / (1.f + expf(-gi));
            float fg = 1.f / (1.f + expf(-gf));
            float g2 = tanhf(gg);
            float og = 1.f / (1.f + expf(-go));
            float cold = (t == 0) ? 0.f : cstate[idx];
            float cnew = fg * cold + ig * g2;
            float hnew = og * tanhf(cnew);
            cstate[idx] = cnew;
            hout[idx]   = hnew;
            if (t == TT - 1) {
                hn[idx] = hnew;
                cn[idx] = cnew;
            }
        }
    }
}

extern "C" void kernel_launch(void* const* d_in, const int* in_sizes, int n_in,
                              void* d_out, int out_size, void* d_ws, size_t ws_size,
                              hipStream_t stream) {
    const float* input_ = (const float*)d_in[0];
    // d_in[1] = ranges (int64, unused), d_in[2] = lengths (int64, unused)
    const float* Wih = (const float*)d_in[3];
    const float* Whh = (const float*)d_in[4];
    const float* bih = (const float*)d_in[5];
    const float* bhh = (const float*)d_in[6];

    float* out    = (float*)d_out;
    float* cstate = (float*)d_ws;   // BSZ*HSZ floats = 2 MB

    float* hn = out + (size_t)TT * BSZ * HSZ;
    float* cn = hn + (size_t)BSZ * HSZ;

    dim3 grid(HSZ / HH, BSZ / BB);  // (16, 8) = 128 blocks
    for (int t = 0; t < TT; ++t) {
        const float* x  = input_ + (size_t)t * BSZ * ISZ;
        const float* hp = (t > 0) ? (out + (size_t)(t - 1) * BSZ * HSZ) : nullptr;
        float* ho = out + (size_t)t * BSZ * HSZ;
        lstm_step_kernel<<<grid, 256, 0, stream>>>(
            x, hp, Wih, Whh, bih, bhh, cstate, ho, hn, cn, t);
    }
}

// Round 2
// 2358.308 us; speedup vs baseline: 8.5411x; 8.5411x over previous
//
#include <hip/hip_runtime.h>
#include <math.h>

#define TT  64
#define BSZ 512
#define ISZ 512
#define HSZ 1024

typedef short bf16x8 __attribute__((ext_vector_type(8)));
typedef float f32x4 __attribute__((ext_vector_type(4)));
typedef unsigned short u16x8 __attribute__((ext_vector_type(8)));

__device__ __forceinline__ unsigned short f2bf(float f) {
    unsigned int u = __float_as_uint(f);
    unsigned int r = u + 0x7FFFu + ((u >> 16) & 1u);   // round-to-nearest-even
    return (unsigned short)(r >> 16);
}

__global__ void cast_f32_to_bf16(const float* __restrict__ in,
                                 unsigned short* __restrict__ out, int n8) {
    int i = blockIdx.x * blockDim.x + threadIdx.x;
    if (i >= n8) return;
    const float4* p = (const float4*)(in + (size_t)i * 8);
    float4 v0 = p[0], v1 = p[1];
    u16x8 o;
    o[0] = f2bf(v0.x); o[1] = f2bf(v0.y); o[2] = f2bf(v0.z); o[3] = f2bf(v0.w);
    o[4] = f2bf(v1.x); o[5] = f2bf(v1.y); o[6] = f2bf(v1.z); o[7] = f2bf(v1.w);
    *(u16x8*)(out + (size_t)i * 8) = o;
}

__global__ void bias_combine(const float* __restrict__ a,
                             const float* __restrict__ b,
                             float* __restrict__ o) {
    int i = blockIdx.x * blockDim.x + threadIdx.x;
    if (i < 4 * HSZ) o[i] = a[i] + b[i];
}

// One LSTM step. Per block: 64(b) x 32(h) x 4 gates. 4 waves, each 32x16x4g.
// Fragments loaded directly from global (bf16, K-contiguous 16B per lane).
__global__ __launch_bounds__(256) void lstm_step_mfma(
    const unsigned short* __restrict__ xb,    // [BSZ, ISZ] bf16, step slice
    const unsigned short* __restrict__ hb,    // [BSZ, HSZ] bf16 prev h (null at t=0)
    const unsigned short* __restrict__ Wihb,  // [4H, ISZ] bf16
    const unsigned short* __restrict__ Whhb,  // [4H, HSZ] bf16
    const float* __restrict__ bias,           // [4H] = b_ih + b_hh
    float* __restrict__ cstate,               // [BSZ, HSZ] fp32
    float* __restrict__ hout,                 // fp32 out slice [BSZ, HSZ]
    unsigned short* __restrict__ hbnext,      // bf16 h for next step
    float* __restrict__ hn, float* __restrict__ cn,
    int t)
{
    const int lane = threadIdx.x & 63;
    const int wave = threadIdx.x >> 6;
    const int wm = wave & 1;          // batch half within block
    const int wh = wave >> 1;         // hidden half within block
    const int b0 = blockIdx.y * 64 + wm * 32;
    const int h0 = blockIdx.x * 32 + wh * 16;
    const int lr = lane & 15;
    const int kb = (lane >> 4) * 8;

    const f32x4 z = {0.f, 0.f, 0.f, 0.f};
    f32x4 acc[4][2];
    #pragma unroll
    for (int g = 0; g < 4; ++g) { acc[g][0] = z; acc[g][1] = z; }

    // ---- x @ W_ih^T  (K = ISZ = 512) ----
    {
        const unsigned short* ap = xb + (size_t)(b0 + lr) * ISZ + kb;
        const unsigned short* bp = Wihb + (size_t)(h0 + lr) * ISZ + kb;
        #pragma unroll 2
        for (int k = 0; k < ISZ; k += 32) {
            bf16x8 a0 = *(const bf16x8*)(ap + k);
            bf16x8 a1 = *(const bf16x8*)(ap + 16 * ISZ + k);
            #pragma unroll
            for (int g = 0; g < 4; ++g) {
                bf16x8 bg = *(const bf16x8*)(bp + (size_t)g * (HSZ * ISZ) + k);
                acc[g][0] = __builtin_amdgcn_mfma_f32_16x16x32_bf16(a0, bg, acc[g][0], 0, 0, 0);
                acc[g][1] = __builtin_amdgcn_mfma_f32_16x16x32_bf16(a1, bg, acc[g][1], 0, 0, 0);
            }
        }
    }
    // ---- h @ W_hh^T  (K = HSZ = 1024), skipped at t=0 (h0 == 0) ----
    if (hb) {
        const unsigned short* ap = hb + (size_t)(b0 + lr) * HSZ + kb;
        const unsigned short* bp = Whhb + (size_t)(h0 + lr) * HSZ + kb;
        #pragma unroll 2
        for (int k = 0; k < HSZ; k += 32) {
            bf16x8 a0 = *(const bf16x8*)(ap + k);
            bf16x8 a1 = *(const bf16x8*)(ap + 16 * HSZ + k);
            #pragma unroll
            for (int g = 0; g < 4; ++g) {
                bf16x8 bg = *(const bf16x8*)(bp + (size_t)g * (HSZ * HSZ) + k);
                acc[g][0] = __builtin_amdgcn_mfma_f32_16x16x32_bf16(a0, bg, acc[g][0], 0, 0, 0);
                acc[g][1] = __builtin_amdgcn_mfma_f32_16x16x32_bf16(a1, bg, acc[g][1], 0, 0, 0);
            }
        }
    }

    // ---- fused LSTM pointwise epilogue (all gate accs are lane-local) ----
    const float bi0 = bias[0 * HSZ + h0 + lr];
    const float bi1 = bias[1 * HSZ + h0 + lr];
    const float bi2 = bias[2 * HSZ + h0 + lr];
    const float bi3 = bias[3 * HSZ + h0 + lr];
    const int rbase = (lane >> 4) * 4;

    #pragma unroll
    for (int mt = 0; mt < 2; ++mt) {
        #pragma unroll
        for (int r = 0; r < 4; ++r) {
            const int b = b0 + mt * 16 + rbase + r;
            const size_t idx = (size_t)b * HSZ + h0 + lr;
            float gi = acc[0][mt][r] + bi0;
            float gf = acc[1][mt][r] + bi1;
            float gg = acc[2][mt][r] + bi2;
            float go = acc[3][mt][r] + bi3;
            float ig = 1.f / (1.f + __expf(-gi));
            float fg = 1.f / (1.f + __expf(-gf));
            float gv = 1.f - 2.f / (__expf(2.f * gg) + 1.f);   // tanh
            float og = 1.f / (1.f + __expf(-go));
            float cold = t ? cstate[idx] : 0.f;
            float cnew = fg * cold + ig * gv;
            float hv = og * (1.f - 2.f / (__expf(2.f * cnew) + 1.f));
            cstate[idx] = cnew;
            hout[idx] = hv;
            hbnext[idx] = f2bf(hv);
            if (t == TT - 1) { hn[idx] = hv; cn[idx] = cnew; }
        }
    }
}

extern "C" void kernel_launch(void* const* d_in, const int* in_sizes, int n_in,
                              void* d_out, int out_size, void* d_ws, size_t ws_size,
                              hipStream_t stream) {
    const float* input_ = (const float*)d_in[0];
    // d_in[1] = ranges (unused), d_in[2] = lengths (unused)
    const float* Wih = (const float*)d_in[3];
    const float* Whh = (const float*)d_in[4];
    const float* bih = (const float*)d_in[5];
    const float* bhh = (const float*)d_in[6];

    char* ws = (char*)d_ws;
    unsigned short* Wihb  = (unsigned short*)(ws);                 //  4 MB
    unsigned short* Whhb  = (unsigned short*)(ws + 4194304);       //  8 MB
    unsigned short* xb    = (unsigned short*)(ws + 12582912);      // 32 MB
    float*          bias  = (float*)(ws + 46137344);               // 16 KB
    float*          cst   = (float*)(ws + 46153728);               //  2 MB
    unsigned short* hbuf0 = (unsigned short*)(ws + 48250880);      //  1 MB
    unsigned short* hbuf1 = (unsigned short*)(ws + 49299456);      //  1 MB

    cast_f32_to_bf16<<<1024, 256, 0, stream>>>(Wih, Wihb, (4 * HSZ * ISZ) / 8);
    cast_f32_to_bf16<<<2048, 256, 0, stream>>>(Whh, Whhb, (4 * HSZ * HSZ) / 8);
    cast_f32_to_bf16<<<8192, 256, 0, stream>>>(input_, xb, (TT * BSZ * ISZ) / 8);
    bias_combine<<<16, 256, 0, stream>>>(bih, bhh, bias);

    float* out = (float*)d_out;
    float* hn = out + (size_t)TT * BSZ * HSZ;
    float* cn = hn + (size_t)BSZ * HSZ;

    dim3 grid(HSZ / 32, BSZ / 64);   // (32, 8) = 256 blocks = 1 per CU
    for (int t = 0; t < TT; ++t) {
        const unsigned short* xbt = xb + (size_t)t * BSZ * ISZ;
        const unsigned short* hbp = t ? (((t - 1) & 1) ? hbuf1 : hbuf0) : nullptr;
        unsigned short* hbn = (t & 1) ? hbuf1 : hbuf0;
        float* ho = out + (size_t)t * BSZ * HSZ;
        lstm_step_mfma<<<grid, 256, 0, stream>>>(
            xbt, hbp, Wihb, Whhb, bias, cst, ho, hbn, hn, cn, t);
    }
}

// Round 3
// 2060.200 us; speedup vs baseline: 9.7770x; 1.1447x over previous
//
#include <hip/hip_runtime.h>

#define TT  64
#define BSZ 512
#define ISZ 512
#define HSZ 1024
#define KCH 64                      // k elements per chunk
#define NCH_X (ISZ / KCH)           // 8
#define NCH_H (HSZ / KCH)           // 16

typedef short bf16x8 __attribute__((ext_vector_type(8)));
typedef float f32x4 __attribute__((ext_vector_type(4)));
typedef unsigned short u16x8 __attribute__((ext_vector_type(8)));

typedef const __attribute__((address_space(1))) unsigned int* gas_t;
typedef __attribute__((address_space(3))) unsigned int* las_t;

__device__ __forceinline__ unsigned short f2bf(float f) {
    unsigned int u = __float_as_uint(f);
    unsigned int r = u + 0x7FFFu + ((u >> 16) & 1u);   // RNE
    return (unsigned short)(r >> 16);
}

__global__ void cast_f32_to_bf16(const float* __restrict__ in,
                                 unsigned short* __restrict__ out, int n8) {
    int i = blockIdx.x * blockDim.x + threadIdx.x;
    if (i >= n8) return;
    const float4* p = (const float4*)(in + (size_t)i * 8);
    float4 v0 = p[0], v1 = p[1];
    u16x8 o;
    o[0] = f2bf(v0.x); o[1] = f2bf(v0.y); o[2] = f2bf(v0.z); o[3] = f2bf(v0.w);
    o[4] = f2bf(v1.x); o[5] = f2bf(v1.y); o[6] = f2bf(v1.z); o[7] = f2bf(v1.w);
    *(u16x8*)(out + (size_t)i * 8) = o;
}

__global__ void bias_combine(const float* __restrict__ a,
                             const float* __restrict__ b,
                             float* __restrict__ o) {
    int i = blockIdx.x * blockDim.x + threadIdx.x;
    if (i < 4 * HSZ) o[i] = a[i] + b[i];
}

// Stage one K-chunk (A: 256 rows x 64k, W: 64 rows x 64k) via global_load_lds,
// source pre-swizzled so LDS[r][kb] = G[r][kb ^ ((r&7)<<4)]  (T2 both-sides).
__device__ __forceinline__ void stage_chunk(
    const unsigned short* __restrict__ As, int lda,
    const unsigned short* __restrict__ Ws, int ldw, int k0,
    unsigned short* Ab, unsigned short* Wb,
    int bb0, int h0, int wv, int lane)
{
    const int sub = lane >> 3;                       // 0..7 (row within 8-row group)
    const int kc8 = (((lane & 7) ^ sub)) * 8;        // swizzled k element offset
    #pragma unroll
    for (int i = 0; i < 8; ++i) {                    // A: wave covers rows wv*64..+63
        const int rl = wv * 64 + i * 8;
        const unsigned short* g = As + (size_t)(bb0 + rl + sub) * lda + k0 + kc8;
        __builtin_amdgcn_global_load_lds((gas_t)g, (las_t)(Ab + rl * KCH), 16, 0, 0);
    }
    #pragma unroll
    for (int i = 0; i < 2; ++i) {                    // W: wave wv stages gate wv rows
        const int rl = wv * 16 + i * 8;
        const unsigned short* g = Ws + (size_t)((size_t)wv * HSZ + h0 + i * 8 + sub) * ldw + k0 + kc8;
        __builtin_amdgcn_global_load_lds((gas_t)g, (las_t)(Wb + rl * KCH), 16, 0, 0);
    }
}

// One LSTM step. 128 blocks = 2 b-tiles(256) x 64 h-tiles(16h).
// 4 waves; wave tile 64b x 64cols, the 4 N-frags = the 4 gates (lane-local epilogue).
__global__ __launch_bounds__(256) void lstm_step(
    const unsigned short* __restrict__ xb,    // [BSZ, ISZ] bf16 slice
    const unsigned short* __restrict__ hb,    // [BSZ, HSZ] bf16 prev h (t>0)
    const unsigned short* __restrict__ Wihb,  // [4H, ISZ]
    const unsigned short* __restrict__ Whhb,  // [4H, HSZ]
    const float* __restrict__ bias,           // [4H]
    float* __restrict__ cstate,
    float* __restrict__ hout,
    unsigned short* __restrict__ hbnext,
    float* __restrict__ hn, float* __restrict__ cn,
    int t)
{
    __shared__ unsigned short Al[2][256 * KCH];   // 2 x 32 KB
    __shared__ unsigned short Wl[2][64 * KCH];    // 2 x  8 KB

    const int lane = threadIdx.x & 63;
    const int wv   = threadIdx.x >> 6;
    const int lr   = lane & 15;
    const int kh   = lane >> 4;                  // 0..3
    const int h0   = blockIdx.x * 16;
    const int bb0  = blockIdx.y * 256;

    const f32x4 z = {0.f, 0.f, 0.f, 0.f};
    f32x4 acc[4][4];                             // [m-frag][gate]
    #pragma unroll
    for (int m = 0; m < 4; ++m)
        #pragma unroll
        for (int g = 0; g < 4; ++g) acc[m][g] = z;

    const int nch = t ? (NCH_X + NCH_H) : NCH_X;

    // chunk c -> source matrices
    #define CHUNK_SRC(c, As, lda, Ws, ldw, k0)                        \
        const unsigned short *As, *Ws; int lda, ldw, k0;              \
        if ((c) < NCH_X) { As = xb; lda = ISZ; k0 = (c) * KCH; Ws = Wihb; ldw = ISZ; } \
        else             { As = hb; lda = HSZ; k0 = ((c) - NCH_X) * KCH; Ws = Whhb; ldw = HSZ; }

    { CHUNK_SRC(0, As, lda, Ws, ldw, k0)
      stage_chunk(As, lda, Ws, ldw, k0, Al[0], Wl[0], bb0, h0, wv, lane); }

    // per-lane frag read byte offsets (swizzled): base k-byte = kh*16, XOR (lr&7)<<4
    const int swz = (lr & 7) << 4;
    const char* AlBase = (const char*)&Al[0][0];
    const char* WlBase = (const char*)&Wl[0][0];

    for (int c = 0; c < nch; ++c) {
        const int buf = c & 1;
        if (c + 1 < nch) {
            CHUNK_SRC(c + 1, As, lda, Ws, ldw, k0)
            stage_chunk(As, lda, Ws, ldw, k0, Al[buf ^ 1], Wl[buf ^ 1], bb0, h0, wv, lane);
            asm volatile("s_waitcnt vmcnt(10)" ::: "memory");   // drain stage(c), keep stage(c+1) in flight
        } else {
            asm volatile("s_waitcnt vmcnt(0)" ::: "memory");
        }
        __builtin_amdgcn_sched_barrier(0);
        __builtin_amdgcn_s_barrier();

        const char* Ac = AlBase + (size_t)buf * (256 * KCH * 2);
        const char* Wc = WlBase + (size_t)buf * (64 * KCH * 2);
        #pragma unroll
        for (int ks = 0; ks < 2; ++ks) {
            const int kb = ks * (KCH) + kh * 16;   // byte offset within row (row = KCH*2 = 128B)
            bf16x8 bf[4], af[4];
            #pragma unroll
            for (int g = 0; g < 4; ++g) {
                const int row = g * 16 + lr;
                bf[g] = *(const bf16x8*)(Wc + row * (KCH * 2) + (kb ^ swz));
            }
            #pragma unroll
            for (int m = 0; m < 4; ++m) {
                const int row = wv * 64 + m * 16 + lr;
                af[m] = *(const bf16x8*)(Ac + row * (KCH * 2) + (kb ^ swz));
            }
            #pragma unroll
            for (int m = 0; m < 4; ++m)
                #pragma unroll
                for (int g = 0; g < 4; ++g)
                    acc[m][g] = __builtin_amdgcn_mfma_f32_16x16x32_bf16(af[m], bf[g], acc[m][g], 0, 0, 0);
        }
        __builtin_amdgcn_s_barrier();
    }

    // ---- fused LSTM pointwise epilogue (4 gates lane-local) ----
    const int n = h0 + lr;
    const float bi0 = bias[0 * HSZ + n];
    const float bi1 = bias[1 * HSZ + n];
    const float bi2 = bias[2 * HSZ + n];
    const float bi3 = bias[3 * HSZ + n];
    const int rb = kh * 4;

    #pragma unroll
    for (int m = 0; m < 4; ++m) {
        #pragma unroll
        for (int r = 0; r < 4; ++r) {
            const int b = bb0 + wv * 64 + m * 16 + rb + r;
            const size_t idx = (size_t)b * HSZ + n;
            float gi = acc[m][0][r] + bi0;
            float gf = acc[m][1][r] + bi1;
            float gg = acc[m][2][r] + bi2;
            float go = acc[m][3][r] + bi3;
            float ig = 1.f / (1.f + __expf(-gi));
            float fg = 1.f / (1.f + __expf(-gf));
            float gv = 1.f - 2.f / (__expf(2.f * gg) + 1.f);
            float og = 1.f / (1.f + __expf(-go));
            float cold = t ? cstate[idx] : 0.f;
            float cnew = fg * cold + ig * gv;
            float hv = og * (1.f - 2.f / (__expf(2.f * cnew) + 1.f));
            cstate[idx] = cnew;
            hout[idx] = hv;
            hbnext[idx] = f2bf(hv);
            if (t == TT - 1) { hn[idx] = hv; cn[idx] = cnew; }
        }
    }
}

extern "C" void kernel_launch(void* const* d_in, const int* in_sizes, int n_in,
                              void* d_out, int out_size, void* d_ws, size_t ws_size,
                              hipStream_t stream) {
    const float* input_ = (const float*)d_in[0];
    const float* Wih = (const float*)d_in[3];
    const float* Whh = (const float*)d_in[4];
    const float* bih = (const float*)d_in[5];
    const float* bhh = (const float*)d_in[6];

    char* ws = (char*)d_ws;
    unsigned short* Wihb  = (unsigned short*)(ws);                 //  4 MB
    unsigned short* Whhb  = (unsigned short*)(ws + 4194304);       //  8 MB
    unsigned short* xb    = (unsigned short*)(ws + 12582912);      // 32 MB
    float*          bias  = (float*)(ws + 46137344);               // 16 KB
    float*          cst   = (float*)(ws + 46153728);               //  2 MB
    unsigned short* hbuf0 = (unsigned short*)(ws + 48250880);      //  1 MB
    unsigned short* hbuf1 = (unsigned short*)(ws + 49299456);      //  1 MB

    cast_f32_to_bf16<<<1024, 256, 0, stream>>>(Wih, Wihb, (4 * HSZ * ISZ) / 8);
    cast_f32_to_bf16<<<2048, 256, 0, stream>>>(Whh, Whhb, (4 * HSZ * HSZ) / 8);
    cast_f32_to_bf16<<<8192, 256, 0, stream>>>(input_, xb, (TT * BSZ * ISZ) / 8);
    bias_combine<<<16, 256, 0, stream>>>(bih, bhh, bias);

    float* out = (float*)d_out;
    float* hn = out + (size_t)TT * BSZ * HSZ;
    float* cn = hn + (size_t)BSZ * HSZ;

    dim3 grid(HSZ / 16, BSZ / 256);   // (64, 2) = 128 blocks
    for (int t = 0; t < TT; ++t) {
        const unsigned short* xbt = xb + (size_t)t * BSZ * ISZ;
        const unsigned short* hbp = t ? (((t - 1) & 1) ? hbuf1 : hbuf0) : nullptr;
        unsigned short* hbn = (t & 1) ? hbuf1 : hbuf0;
        float* ho = out + (size_t)t * BSZ * HSZ;
        lstm_step<<<grid, 256, 0, stream>>>(
            xbt, hbp, Wihb, Whhb, bias, cst, ho, hbn, hn, cn, t);
    }
}

// Round 4
// 1704.010 us; speedup vs baseline: 11.8207x; 1.2090x over previous
//
#include <hip/hip_runtime.h>

#define TT  64
#define BSZ 512
#define ISZ 512
#define HSZ 1024

typedef short bf16x8 __attribute__((ext_vector_type(8)));
typedef float f32x4 __attribute__((ext_vector_type(4)));
typedef unsigned short u16x8 __attribute__((ext_vector_type(8)));

typedef const __attribute__((address_space(1))) unsigned int* gas_t;
typedef __attribute__((address_space(3))) unsigned int* las_t;

__device__ __forceinline__ unsigned short f2bf(float f) {
    unsigned int u = __float_as_uint(f);
    unsigned int r = u + 0x7FFFu + ((u >> 16) & 1u);   // RNE
    return (unsigned short)(r >> 16);
}

__global__ void cast_f32_to_bf16(const float* __restrict__ in,
                                 unsigned short* __restrict__ out, int n8) {
    int i = blockIdx.x * blockDim.x + threadIdx.x;
    if (i >= n8) return;
    const float4* p = (const float4*)(in + (size_t)i * 8);
    float4 v0 = p[0], v1 = p[1];
    u16x8 o;
    o[0] = f2bf(v0.x); o[1] = f2bf(v0.y); o[2] = f2bf(v0.z); o[3] = f2bf(v0.w);
    o[4] = f2bf(v1.x); o[5] = f2bf(v1.y); o[6] = f2bf(v1.z); o[7] = f2bf(v1.w);
    *(u16x8*)(out + (size_t)i * 8) = o;
}

__global__ void bias_combine(const float* __restrict__ a,
                             const float* __restrict__ b,
                             float* __restrict__ o) {
    int i = blockIdx.x * blockDim.x + threadIdx.x;
    if (i < 4 * HSZ) o[i] = a[i] + b[i];
}

// Stage one 128-row x 64-col bf16 K-chunk of A and W into LDS (linear dest,
// source k-offset pre-swizzled so read-side XOR is conflict-free; rule-21 pair).
__device__ __forceinline__ void stage(
    const unsigned short* __restrict__ A, int lda,
    const unsigned short* __restrict__ W, int ldw,
    int k0, int bb0, int hh0,
    unsigned short* Abuf, unsigned short* Wbuf, int wv, int lane)
{
    const int sub = lane >> 3;                    // row within 8-row group
    const int swk = ((lane & 7) ^ sub) * 8;       // swizzled k element offset
    #pragma unroll
    for (int i = 0; i < 4; ++i) {
        const int tr8 = (wv * 4 + i) * 8;
        const int tr = tr8 + sub;
        const unsigned short* g = A + (size_t)(bb0 + tr) * lda + k0 + swk;
        __builtin_amdgcn_global_load_lds((gas_t)g, (las_t)(Abuf + tr8 * 64), 16, 0, 0);
    }
    #pragma unroll
    for (int i = 0; i < 4; ++i) {
        const int tr8 = (wv * 4 + i) * 8;
        const int tr = tr8 + sub;                 // tile row: g*32 + hc
        const int wrow = hh0 + (tr & 31) + (tr >> 5) * 1024;
        const unsigned short* g = W + (size_t)wrow * ldw + k0 + swk;
        __builtin_amdgcn_global_load_lds((gas_t)g, (las_t)(Wbuf + tr8 * 64), 16, 0, 0);
    }
}

// One launch = 128 h-blocks (recurrent GEMM step t + LSTM epilogue)
//            + 128 x-blocks (input projection for step t+1 -> xg ping-pong).
// Block tile 128b x (4g x 32h); 4 waves, wave tile 64b x (4g x 16h) = m4n4.
__global__ __launch_bounds__(256) void lstm_fused(
    const unsigned short* __restrict__ xnx,   // x slice for x-part's step
    const unsigned short* __restrict__ hb,    // h_{t-1} bf16 (t>0)
    const unsigned short* __restrict__ Wihb,  // [4096, 512]
    const unsigned short* __restrict__ Whhb,  // [4096, 1024]
    const float* __restrict__ bias,           // [4096]
    const float* __restrict__ xg_in,          // [512, 4096] fp32 (h-blocks read)
    float* __restrict__ xg_out,               // [512, 4096] fp32 (x-blocks write)
    float* __restrict__ cstate,
    float* __restrict__ hout,
    unsigned short* __restrict__ hbnext,
    float* __restrict__ hn, float* __restrict__ cn,
    int t, int n_h)
{
    __shared__ unsigned short Ab[2][128 * 64];   // 2 x 16 KB
    __shared__ unsigned short Wb[2][128 * 64];   // 2 x 16 KB

    const int bid  = blockIdx.x;
    const bool ish = bid < n_h;
    const int lbid = ish ? bid : bid - n_h;
    // XCD-grouped mapping: blocks with the same hh-range land on the same XCD
    const int xcd = lbid & 7;
    const int idx = lbid >> 3;
    const int hh0 = (xcd * 4 + (idx & 3)) * 32;   // 32 h-cols per block
    const int bb0 = (idx >> 2) * 128;             // 128 b-rows per block

    const unsigned short *A, *W;
    int lda, ldw, nch;
    if (ish) { A = hb;  lda = HSZ; W = Whhb; ldw = HSZ; nch = t ? 16 : 0; }
    else     { A = xnx; lda = ISZ; W = Wihb; ldw = ISZ; nch = 8; }

    const int lane = threadIdx.x & 63;
    const int wv   = threadIdx.x >> 6;
    const int wx   = wv & 1;            // h-16 half
    const int wy   = wv >> 1;           // b-64 half
    const int lr   = lane & 15;
    const int kq   = lane >> 4;

    const f32x4 z = {0.f, 0.f, 0.f, 0.f};
    f32x4 acc[4][4];                    // [m][gate]
    #pragma unroll
    for (int m = 0; m < 4; ++m)
        #pragma unroll
        for (int g = 0; g < 4; ++g) acc[m][g] = z;

    if (nch) stage(A, lda, W, ldw, 0, bb0, hh0, Ab[0], Wb[0], wv, lane);

    const int swz = (lr & 7) << 4;
    for (int c = 0; c < nch; ++c) {
        const int buf = c & 1;
        if (c + 1 < nch) {
            stage(A, lda, W, ldw, (c + 1) * 64, bb0, hh0, Ab[buf ^ 1], Wb[buf ^ 1], wv, lane);
            asm volatile("s_waitcnt vmcnt(8)" ::: "memory");   // drain stage(c) only
        } else {
            asm volatile("s_waitcnt vmcnt(0)" ::: "memory");
        }
        __builtin_amdgcn_sched_barrier(0);
        __builtin_amdgcn_s_barrier();

        const char* Ac = (const char*)Ab[buf];
        const char* Wc = (const char*)Wb[buf];
        #pragma unroll
        for (int ks = 0; ks < 2; ++ks) {
            const int kb = ks * 64 + kq * 16;     // byte offset within 128B row
            bf16x8 wf[4], af[4];
            #pragma unroll
            for (int g = 0; g < 4; ++g) {
                const int tr = g * 32 + wx * 16 + lr;
                wf[g] = *(const bf16x8*)(Wc + tr * 128 + (kb ^ swz));
            }
            #pragma unroll
            for (int m = 0; m < 4; ++m) {
                const int tr = wy * 64 + m * 16 + lr;
                af[m] = *(const bf16x8*)(Ac + tr * 128 + (kb ^ swz));
            }
            #pragma unroll
            for (int m = 0; m < 4; ++m)
                #pragma unroll
                for (int g = 0; g < 4; ++g)
                    acc[m][g] = __builtin_amdgcn_mfma_f32_16x16x32_bf16(af[m], wf[g], acc[m][g], 0, 0, 0);
        }
        __builtin_amdgcn_s_barrier();
    }

    const int n = hh0 + wx * 16 + lr;             // h column 0..1023
    const int brow0 = bb0 + wy * 64;

    if (ish) {
        // ---- LSTM pointwise epilogue: gates = acc + xg_in ----
        #pragma unroll
        for (int m = 0; m < 4; ++m) {
            #pragma unroll
            for (int r = 0; r < 4; ++r) {
                const int b = brow0 + m * 16 + kq * 4 + r;
                const size_t idx2 = (size_t)b * HSZ + n;
                const size_t xgi = (size_t)b * (4 * HSZ) + n;
                float gi = acc[m][0][r] + xg_in[xgi + 0 * HSZ];
                float gf = acc[m][1][r] + xg_in[xgi + 1 * HSZ];
                float gg = acc[m][2][r] + xg_in[xgi + 2 * HSZ];
                float go = acc[m][3][r] + xg_in[xgi + 3 * HSZ];
                float ig = 1.f / (1.f + __expf(-gi));
                float fg = 1.f / (1.f + __expf(-gf));
                float gv = 1.f - 2.f / (__expf(2.f * gg) + 1.f);
                float og = 1.f / (1.f + __expf(-go));
                float cold = t ? cstate[idx2] : 0.f;
                float cnew = fg * cold + ig * gv;
                float hv = og * (1.f - 2.f / (__expf(2.f * cnew) + 1.f));
                cstate[idx2] = cnew;
                hout[idx2] = hv;
                hbnext[idx2] = f2bf(hv);
                if (t == TT - 1) { hn[idx2] = hv; cn[idx2] = cnew; }
            }
        }
    } else {
        // ---- x-projection epilogue: xg_out = acc + bias ----
        float bv[4];
        #pragma unroll
        for (int g = 0; g < 4; ++g) bv[g] = bias[g * HSZ + n];
        #pragma unroll
        for (int m = 0; m < 4; ++m) {
            #pragma unroll
            for (int r = 0; r < 4; ++r) {
                const int b = brow0 + m * 16 + kq * 4 + r;
                const size_t xgi = (size_t)b * (4 * HSZ) + n;
                #pragma unroll
                for (int g = 0; g < 4; ++g)
                    xg_out[xgi + (size_t)g * HSZ] = acc[m][g][r] + bv[g];
            }
        }
    }
}

extern "C" void kernel_launch(void* const* d_in, const int* in_sizes, int n_in,
                              void* d_out, int out_size, void* d_ws, size_t ws_size,
                              hipStream_t stream) {
    const float* input_ = (const float*)d_in[0];
    const float* Wih = (const float*)d_in[3];
    const float* Whh = (const float*)d_in[4];
    const float* bih = (const float*)d_in[5];
    const float* bhh = (const float*)d_in[6];

    char* ws = (char*)d_ws;
    unsigned short* Wihb  = (unsigned short*)(ws);                 //  4 MB
    unsigned short* Whhb  = (unsigned short*)(ws + (4u << 20));    //  8 MB
    unsigned short* xb    = (unsigned short*)(ws + (12u << 20));   // 33.6 MB
    float*          bias  = (float*)(ws + (46u << 20));            // 16 KB
    float*          cst   = (float*)(ws + (47u << 20));            //  2 MB
    unsigned short* hbuf0 = (unsigned short*)(ws + (49u << 20));   //  1 MB
    unsigned short* hbuf1 = (unsigned short*)(ws + (50u << 20));   //  1 MB
    float*          xg0   = (float*)(ws + (51u << 20));            //  8 MB
    float*          xg1   = (float*)(ws + (59u << 20));            //  8 MB

    cast_f32_to_bf16<<<1024, 256, 0, stream>>>(Wih, Wihb, (4 * HSZ * ISZ) / 8);
    cast_f32_to_bf16<<<2048, 256, 0, stream>>>(Whh, Whhb, (4 * HSZ * HSZ) / 8);
    cast_f32_to_bf16<<<8192, 256, 0, stream>>>(input_, xb, (TT * BSZ * ISZ) / 8);
    bias_combine<<<16, 256, 0, stream>>>(bih, bhh, bias);

    float* out = (float*)d_out;
    float* hn = out + (size_t)TT * BSZ * HSZ;
    float* cn = hn + (size_t)BSZ * HSZ;

    // Prologue: x-projection for step 0 only (128 x-blocks)
    lstm_fused<<<128, 256, 0, stream>>>(
        xb, nullptr, Wihb, Whhb, bias, nullptr, xg0,
        cst, out, hbuf0, hn, cn, 0, /*n_h=*/0);

    for (int t = 0; t < TT; ++t) {
        const unsigned short* xnx = xb + (size_t)((t + 1 < TT) ? t + 1 : t) * BSZ * ISZ;
        const unsigned short* hbp = t ? ((t & 1) ? hbuf0 : hbuf1) : nullptr;
        unsigned short* hbn = (t & 1) ? hbuf1 : hbuf0;
        const float* xgi = (t & 1) ? xg1 : xg0;
        float* xgo = (t & 1) ? xg0 : xg1;
        float* ho = out + (size_t)t * BSZ * HSZ;
        const int grid = (t + 1 < TT) ? 256 : 128;
        lstm_fused<<<grid, 256, 0, stream>>>(
            xnx, hbp, Wihb, Whhb, bias, xgi, xgo,
            cst, ho, hbn, hn, cn, t, /*n_h=*/128);
    }
}